// Round 9
// baseline (78.509 us; speedup 1.0000x reference)
//
#include <hip/hip_runtime.h>

#define T_LEN 262144
#define B_SZ 8
#define CHUNK 8192
#define HALO 4096
#define NTHREADS 1024
#define NGROUPS ((CHUNK + HALO) / 4)    // 3072 float4-groups per block frame
#define CHUNKS_PER_ROW (T_LEN / CHUNK)  // 32
#define NBLOCKS (B_SZ * CHUNKS_PER_ROW) // 256
#define LOG2E 1.4426950408889634f
#define NEG2LOG2E (-2.8853900817779268f)
#define NEGLOG2E  (-1.4426950408889634f)

typedef float f32x2 __attribute__((ext_vector_type(2)));
typedef float f32x4 __attribute__((ext_vector_type(4)));

__device__ __forceinline__ float frcp(float x)  { return __builtin_amdgcn_rcpf(x); }
__device__ __forceinline__ float fexp2(float x) { return __builtin_amdgcn_exp2f(x); }
__device__ __forceinline__ f32x4 splat(float s) { f32x4 r = {s, s, s, s}; return r; }
__device__ __forceinline__ f32x2 pair(float s)  { f32x2 r = {s, s}; return r; }
__device__ __forceinline__ f32x2 lo2(f32x4 v)   { return __builtin_shufflevector(v, v, 0, 1); }
__device__ __forceinline__ f32x2 hi2(f32x4 v)   { return __builtin_shufflevector(v, v, 2, 3); }
__device__ __forceinline__ f32x4 cat4(f32x2 a, f32x2 b) {
    f32x4 r; r.x = a.x; r.y = a.y; r.z = b.x; r.w = b.y; return r;
}

// ---- packed-FP32 (VOP3P) primitives: 2 lanes of f32 per instruction ----
// NOTE (round-8 lesson): the gfx950 assembler REJECTS SGPR sources on
// v_pk_*_f32 — all operands must be VGPRs. Uniform weights therefore get
// pair-splatted into VGPRs once per layer (cheap, amortized).
__device__ __forceinline__ f32x2 pkfma2(f32x2 a, f32x2 b, f32x2 c) {
    f32x2 d;
    asm("v_pk_fma_f32 %0, %1, %2, %3" : "=v"(d) : "v"(a), "v"(b), "v"(c));
    return d;
}
__device__ __forceinline__ f32x2 pkadd2(f32x2 a, f32x2 b) {
    f32x2 d;
    asm("v_pk_add_f32 %0, %1, %2" : "=v"(d) : "v"(a), "v"(b));
    return d;
}
__device__ __forceinline__ f32x2 pksub2(f32x2 a, f32x2 b) {  // a - b
    f32x2 d;
    asm("v_pk_add_f32 %0, %1, %2 neg_lo:[0,1] neg_hi:[0,1]" : "=v"(d) : "v"(a), "v"(b));
    return d;
}
__device__ __forceinline__ f32x2 pkmul2(f32x2 a, f32x2 b) {
    f32x2 d;
    asm("v_pk_mul_f32 %0, %1, %2" : "=v"(d) : "v"(a), "v"(b));
    return d;
}
// f32x4 wrappers (2 VOP3P each); s-variants broadcast a pre-splatted pair
__device__ __forceinline__ f32x4 pfma_s(f32x2 w, f32x4 v, f32x4 a) {
    return cat4(pkfma2(w, lo2(v), lo2(a)), pkfma2(w, hi2(v), hi2(a)));
}
__device__ __forceinline__ f32x4 pfma_v(f32x4 a, f32x4 b, f32x4 c) {
    return cat4(pkfma2(lo2(a), lo2(b), lo2(c)), pkfma2(hi2(a), hi2(b), hi2(c)));
}
__device__ __forceinline__ f32x4 padd_s(f32x2 s, f32x4 b) {
    return cat4(pkadd2(s, lo2(b)), pkadd2(s, hi2(b)));
}
__device__ __forceinline__ f32x4 padd_v(f32x4 a, f32x4 b) {
    return cat4(pkadd2(lo2(a), lo2(b)), pkadd2(hi2(a), hi2(b)));
}
__device__ __forceinline__ f32x4 psub_s(f32x2 s, f32x4 b) {  // s - b
    return cat4(pksub2(s, lo2(b)), pksub2(s, hi2(b)));
}
__device__ __forceinline__ f32x4 pmul_v(f32x4 a, f32x4 b) {
    return cat4(pkmul2(lo2(a), lo2(b)), pkmul2(hi2(a), hi2(b)));
}

// bf16x2 pack (truncating) via single v_perm_b32 per word; unpack leaves the
// neighbor's bits in the low mantissa (<=2^-9 relative noise, ~bf16 rounding)
__device__ __forceinline__ uint2 pk4(f32x4 v) {
    uint2 u;
    u.x = __builtin_amdgcn_perm(__float_as_uint(v.y), __float_as_uint(v.x), 0x07060302u);
    u.y = __builtin_amdgcn_perm(__float_as_uint(v.w), __float_as_uint(v.z), 0x07060302u);
    return u;
}
__device__ __forceinline__ f32x4 up4(uint2 u) {
    f32x4 r;
    r.x = __uint_as_float(u.x << 16);
    r.y = __uint_as_float(u.x);
    r.z = __uint_as_float(u.y << 16);
    r.w = __uint_as_float(u.y);
    return r;
}
// o = tanh(a)*sigmoid(b), af = -2*log2e*a, ag = -log2e*b pre-scaled:
// E1=2^af=e^{-2a}, E2=2^ag=e^{-b}; o = (1-E1)/((1+E1)(1+E2))
__device__ __forceinline__ f32x4 gate4(f32x4 af, f32x4 ag, f32x2 one) {
    f32x4 E1, E2, rc;
    E1.x = fexp2(af.x); E1.y = fexp2(af.y); E1.z = fexp2(af.z); E1.w = fexp2(af.w);
    E2.x = fexp2(ag.x); E2.y = fexp2(ag.y); E2.z = fexp2(ag.z); E2.w = fexp2(ag.w);
    f32x4 d1  = padd_s(one, E1);
    f32x4 den = pfma_v(E2, d1, d1);
    f32x4 num = psub_s(one, E1);
    rc.x = frcp(den.x); rc.y = frcp(den.y); rc.z = frcp(den.z); rc.w = frcp(den.w);
    return pmul_v(num, rc);
}
// conv1->relu->conv2->relu->mu-law expand; exp(|b|*ln256) == exp2(|b|*8)
__device__ __forceinline__ float mulaw(float v, float c1wv, float c1bv, float c2wv, float c2bv) {
    float a  = __builtin_fmaf(c1wv, fmaxf(v, 0.0f), c1bv);
    float b2 = __builtin_fmaf(c2wv, fmaxf(a, 0.0f), c2bv);
    float m  = fexp2(fabsf(b2) * 8.0f) - 1.0f;
    return copysignf(m * (1.0f / 255.0f), b2);
}

// One dilation cycle (10 layers, d=1..512). Thread owns 3 float4 groups
// (w=0: halo G=tid; w=1,2: valid) in fp32 registers; LDS holds bf16x2-packed
// taps, double-buffered, ONE barrier per layer. Buffer parity c is
// compile-time (full unroll) so LDS bases fold; tap reads use ONE base
// address (lowest tap) + compile-time ds-offset immediates 8*DG*{1,2,3}.
// Reach-based halo skip: layer k's output only needed at halo G >= 2^(k+1).
// Zero padding: global t<0 <=> (chunk==0 && w==0).
// NOTE: launch_bounds min-waves MUST stay at 4 — 8 clamps VGPR to 32 and
// causes a scratch-spill storm (round 5).
template <int STAGE>
__global__ __launch_bounds__(NTHREADS, 4)
void stage_kernel(const void* __restrict__ in_,
                  const float* __restrict__ cw, const float* __restrict__ cb,
                  const float* __restrict__ fw, const float* __restrict__ fb,
                  const float* __restrict__ gw, const float* __restrict__ gb,
                  const float* __restrict__ rw, const float* __restrict__ rb,
                  uint2* __restrict__ hout, float* __restrict__ skio,
                  const float* __restrict__ c1w, const float* __restrict__ c1b,
                  const float* __restrict__ c2w, const float* __restrict__ c2b,
                  float2* __restrict__ blockstats)
{
    __shared__ uint2 bufl[2][NGROUPS];       // 2 x 24 KB bf16x2 tap buffers
    __shared__ float red[NTHREADS / 64];

    const int tid = threadIdx.x;
    const int bid = blockIdx.x;
    const int row = bid / CHUNKS_PER_ROW;
    const int chunk = bid % CHUNKS_PER_ROW;
    const int rowbase = row * T_LEN;
    const int base_t = chunk * CHUNK;
    const bool first = (chunk == 0);

    // ---- load own groups (fp32 regs) + publish packed taps to buf 0 ----
    f32x4 h[3];
    if (STAGE == 0) {
        const float* inb = (const float*)in_ + rowbase + base_t - HALO;
        #pragma unroll
        for (int w = 0; w < 3; ++w) {
            int G = tid + w * NTHREADS;
            if (w == 0 && first) h[w] = splat(0.0f);
            else                 h[w] = *(const f32x4*)(inb + 4 * G);
            bufl[0][G] = pk4(h[w]);
        }
    } else {
        const uint2* inb = (const uint2*)in_ + ((rowbase + base_t - HALO) >> 2);
        #pragma unroll
        for (int w = 0; w < 3; ++w) {
            int G = tid + w * NTHREADS;
            uint2 u = (w == 0 && first) ? make_uint2(0u, 0u) : inb[G];
            bufl[0][G] = u;
            h[w] = up4(u);
        }
    }
    f32x4 sk[2];
    if (STAGE == 0) { sk[0] = splat(0.0f); sk[1] = splat(0.0f); }
    else {
        sk[0] = *(const f32x4*)(skio + rowbase + base_t + 4 * tid);
        sk[1] = *(const f32x4*)(skio + rowbase + base_t + 4096 + 4 * tid);
    }
    __syncthreads();

    const f32x2 ONE = pair(1.0f);

    if (STAGE == 0) {
        // causal conv (d=1); weight for tap distance m is cw[4-m]
        f32x2 CW[5];
        #pragma unroll
        for (int j = 0; j < 5; ++j) CW[j] = pair(cw[4 - j]);
        const f32x4 BB = splat(cb[0]);
        #pragma unroll
        for (int w = 0; w < 3; ++w) {
            int G = tid + w * NTHREADS;
            int gm = G - 1; if (w == 0) gm = gm < 0 ? 0 : gm;  // junk-in-halo OK
            f32x4 T = up4(bufl[0][gm]);
            f32x4 hw = h[w];
            f32x4 t1 = __builtin_shufflevector(T, hw, 3, 4, 5, 6);
            f32x4 t2 = __builtin_shufflevector(T, hw, 2, 3, 4, 5);
            f32x4 t3 = __builtin_shufflevector(T, hw, 1, 2, 3, 4);
            f32x4 acc = pfma_s(CW[0], hw, BB);
            acc = pfma_s(CW[1], t1, acc);
            acc = pfma_s(CW[2], t2, acc);
            acc = pfma_s(CW[3], t3, acc);
            acc = pfma_s(CW[4], T, acc);
            if (w == 0 && first) acc = splat(0.0f);
            h[w] = acc;
            bufl[1][G] = pk4(acc);
        }
        __syncthreads();
    }

    // ---- 10 dilated gated layers, one barrier each; c compile-time ----
    #pragma unroll
    for (int k = 0; k < 10; ++k) {
        const int c = (STAGE == 0) ? ((k + 1) & 1) : (k & 1);
        const int d = 1 << k;
        const int L = STAGE * 10 + k;
        const float* fwL = fw + 5 * L;
        const float* gwL = gw + 5 * L;
        f32x2 WF[5], WG[5];
        #pragma unroll
        for (int j = 0; j < 5; ++j) {          // tap j*d uses weight index 4-j
            WF[j] = pair(fwL[4 - j] * NEG2LOG2E);
            WG[j] = pair(gwL[4 - j] * NEGLOG2E);
        }
        const f32x4 FB = splat(fb[L] * NEG2LOG2E), GB = splat(gb[L] * NEGLOG2E);
        const f32x2 RW = pair(rw[L]), RB = pair(rb[L]);
        const uint2* __restrict__ bufc = bufl[c];
        uint2* __restrict__ bufd = bufl[c ^ 1];

        #pragma unroll
        for (int w = 0; w < 3; ++w) {
            const int G = tid + w * NTHREADS;
            if (w == 0 && tid < (2 << k)) continue;  // reach expired (k=9: all of w=0)
            f32x4 hw = h[w];
            f32x4 t1, t2, t3, t4;
            if (d >= 4) {
                const int DG = d >> 2;               // taps stay group-aligned
                const uint2* bp = bufc + (G - 4 * DG);  // ONE base; +imm offsets
                t4 = up4(bp[0]);
                t3 = up4(bp[DG]);
                t2 = up4(bp[2 * DG]);
                t1 = up4(bp[3 * DG]);
            } else if (d == 1) {
                f32x4 T = up4(bufc[G - 1]);
                t1 = __builtin_shufflevector(T, hw, 3, 4, 5, 6);
                t2 = __builtin_shufflevector(T, hw, 2, 3, 4, 5);
                t3 = __builtin_shufflevector(T, hw, 1, 2, 3, 4);
                t4 = T;
            } else { // d == 2
                const uint2* bp = bufc + (G - 2);
                f32x4 T2 = up4(bp[0]);
                f32x4 T1 = up4(bp[1]);
                t1 = __builtin_shufflevector(T1, hw, 2, 3, 4, 5);
                t2 = T1;
                t3 = __builtin_shufflevector(T2, T1, 2, 3, 4, 5);
                t4 = T2;
            }
            f32x4 af = pfma_s(WF[0], hw, FB);
            af = pfma_s(WF[1], t1, af); af = pfma_s(WF[2], t2, af);
            af = pfma_s(WF[3], t3, af); af = pfma_s(WF[4], t4, af);
            f32x4 ag = pfma_s(WG[0], hw, GB);
            ag = pfma_s(WG[1], t1, ag); ag = pfma_s(WG[2], t2, ag);
            ag = pfma_s(WG[3], t3, ag); ag = pfma_s(WG[4], t4, ag);
            f32x4 o = gate4(af, ag, ONE);
            f32x4 nh = pfma_s(RW, o, padd_s(RB, hw));
            if (w == 0 && first) nh = splat(0.0f);   // keep t<0 padding exactly 0
            h[w] = nh;
            if (k < 9) bufd[G] = pk4(nh);            // last layer never re-read
            if (w == 1) sk[0] = padd_v(sk[0], o);
            if (w == 2) sk[1] = padd_v(sk[1], o);
        }
        if (k < 9) __syncthreads();
    }

    if (STAGE < 2) {
        uint2* hp = hout + ((rowbase + base_t) >> 2);
        hp[tid]        = pk4(h[1]);                  // packed bf16 handoff
        hp[tid + 1024] = pk4(h[2]);
        *(f32x4*)(skio + rowbase + base_t + 4 * tid)        = sk[0];
        *(f32x4*)(skio + rowbase + base_t + 4096 + 4 * tid) = sk[1];
    } else {
        // fused epilogue + per-block (max, sum-exp) stats
        const float c1wv = c1w[0], c1bv = c1b[0], c2wv = c2w[0], c2bv = c2b[0];
        f32x4 p1, p2;
        p1.x = mulaw(sk[0].x, c1wv, c1bv, c2wv, c2bv);
        p1.y = mulaw(sk[0].y, c1wv, c1bv, c2wv, c2bv);
        p1.z = mulaw(sk[0].z, c1wv, c1bv, c2wv, c2bv);
        p1.w = mulaw(sk[0].w, c1wv, c1bv, c2wv, c2bv);
        p2.x = mulaw(sk[1].x, c1wv, c1bv, c2wv, c2bv);
        p2.y = mulaw(sk[1].y, c1wv, c1bv, c2wv, c2bv);
        p2.z = mulaw(sk[1].z, c1wv, c1bv, c2wv, c2bv);
        p2.w = mulaw(sk[1].w, c1wv, c1bv, c2wv, c2bv);
        *(f32x4*)(skio + rowbase + base_t + 4 * tid)        = p1;
        *(f32x4*)(skio + rowbase + base_t + 4096 + 4 * tid) = p2;

        float pmax = fmaxf(fmaxf(fmaxf(p1.x, p1.y), fmaxf(p1.z, p1.w)),
                           fmaxf(fmaxf(p2.x, p2.y), fmaxf(p2.z, p2.w)));
        #pragma unroll
        for (int off = 32; off; off >>= 1) pmax = fmaxf(pmax, __shfl_xor(pmax, off, 64));
        if ((tid & 63) == 0) red[tid >> 6] = pmax;
        __syncthreads();
        float bmax = red[0];
        #pragma unroll
        for (int i = 1; i < NTHREADS / 64; ++i) bmax = fmaxf(bmax, red[i]);
        __syncthreads();   // red reused below

        float ps = fexp2((p1.x - bmax) * LOG2E) + fexp2((p1.y - bmax) * LOG2E)
                 + fexp2((p1.z - bmax) * LOG2E) + fexp2((p1.w - bmax) * LOG2E)
                 + fexp2((p2.x - bmax) * LOG2E) + fexp2((p2.y - bmax) * LOG2E)
                 + fexp2((p2.z - bmax) * LOG2E) + fexp2((p2.w - bmax) * LOG2E);
        #pragma unroll
        for (int off = 32; off; off >>= 1) ps += __shfl_xor(ps, off, 64);
        if ((tid & 63) == 0) red[tid >> 6] = ps;
        __syncthreads();
        if (tid == 0) {
            float s = 0.0f;
            #pragma unroll
            for (int i = 0; i < NTHREADS / 64; ++i) s += red[i];
            blockstats[bid] = make_float2(bmax, s);
        }
    }
}

// 8 blocks (one per row) x 64 threads: reduce 32 block-stats -> (rowmax, 1/rowsum)
__global__ __launch_bounds__(64)
void combine_kernel(const float2* __restrict__ bs, float2* __restrict__ rs)
{
    const int row = blockIdx.x;
    const int lane = threadIdx.x;
    float bm = -3.0e38f, s = 0.0f;
    if (lane < CHUNKS_PER_ROW) {
        float2 v = bs[row * CHUNKS_PER_ROW + lane];
        bm = v.x; s = v.y;
    }
    float m = bm;
    #pragma unroll
    for (int off = 32; off; off >>= 1) m = fmaxf(m, __shfl_xor(m, off, 64));
    float cc = s * fexp2((bm - m) * LOG2E);
    #pragma unroll
    for (int off = 32; off; off >>= 1) cc += __shfl_xor(cc, off, 64);
    if (lane == 0) rs[row] = make_float2(m, 1.0f / cc);
}

__global__ __launch_bounds__(NTHREADS)
void norm_kernel(float* __restrict__ p, const float2* __restrict__ rs)
{
    const int tid = threadIdx.x, bid = blockIdx.x;
    const int row = bid / CHUNKS_PER_ROW;
    const float2 st = rs[row];
    const int base = row * T_LEN + (bid % CHUNKS_PER_ROW) * CHUNK + 4 * tid;
    #pragma unroll
    for (int part = 0; part < 2; ++part) {
        float* q = p + base + part * 4096;
        f32x4 v = *(const f32x4*)q;
        v.x = fexp2((v.x - st.x) * LOG2E) * st.y;
        v.y = fexp2((v.y - st.x) * LOG2E) * st.y;
        v.z = fexp2((v.z - st.x) * LOG2E) * st.y;
        v.w = fexp2((v.w - st.x) * LOG2E) * st.y;
        *(f32x4*)q = v;
    }
}

extern "C" void kernel_launch(void* const* d_in, const int* in_sizes, int n_in,
                              void* d_out, int out_size, void* d_ws, size_t ws_size,
                              hipStream_t stream)
{
    (void)in_sizes; (void)n_in; (void)out_size; (void)ws_size;
    const float* x   = (const float*)d_in[0];
    const float* cw  = (const float*)d_in[1];
    const float* cb  = (const float*)d_in[2];
    const float* fw  = (const float*)d_in[3];
    const float* fb  = (const float*)d_in[4];
    const float* gw  = (const float*)d_in[5];
    const float* gb  = (const float*)d_in[6];
    const float* rw  = (const float*)d_in[7];
    const float* rb  = (const float*)d_in[8];
    const float* c1w = (const float*)d_in[9];
    const float* c1b = (const float*)d_in[10];
    const float* c2w = (const float*)d_in[11];
    const float* c2b = (const float*)d_in[12];
    float* out = (float*)d_out;

    const size_t NTOT = (size_t)B_SZ * T_LEN;
    uint2*  hA = (uint2*)d_ws;                                  // 4.2 MB packed bf16
    uint2*  hB = (uint2*)((char*)d_ws + NTOT * 2);              // 4.2 MB
    float2* bs = (float2*)((char*)d_ws + NTOT * 4);             // 2 KB
    float2* rs = (float2*)((char*)d_ws + NTOT * 4 + 8192);      // 64 B

    // d_out doubles as the skip accumulator between stages, then holds
    // pre-softmax values, then the final softmax output.
    stage_kernel<0><<<NBLOCKS, NTHREADS, 0, stream>>>(x,  cw, cb, fw, fb, gw, gb, rw, rb,
                                                      hA, out, c1w, c1b, c2w, c2b, bs);
    stage_kernel<1><<<NBLOCKS, NTHREADS, 0, stream>>>(hA, cw, cb, fw, fb, gw, gb, rw, rb,
                                                      hB, out, c1w, c1b, c2w, c2b, bs);
    stage_kernel<2><<<NBLOCKS, NTHREADS, 0, stream>>>(hB, cw, cb, fw, fb, gw, gb, rw, rb,
                                                      nullptr, out, c1w, c1b, c2w, c2b, bs);
    combine_kernel<<<B_SZ, 64, 0, stream>>>(bs, rs);
    norm_kernel<<<NBLOCKS, NTHREADS, 0, stream>>>(out, rs);
}

// Round 11
// 77.418 us; speedup vs baseline: 1.0141x; 1.0141x over previous
//
#include <hip/hip_runtime.h>

#define T_LEN 262144
#define B_SZ 8
#define CHUNK 8192
#define HALO 4096
#define NTHREADS 1024
#define NGROUPS ((CHUNK + HALO) / 4)    // 3072 4-element groups per frame
#define CHUNKS_PER_ROW (T_LEN / CHUNK)  // 32
#define NBLOCKS (B_SZ * CHUNKS_PER_ROW) // 256
#define LOG2E 1.4426950408889634f
#define NEG2LOG2E (-2.8853900817779268f)
#define NEGLOG2E  (-1.4426950408889634f)

typedef float f32x2 __attribute__((ext_vector_type(2)));
typedef float f32x4 __attribute__((ext_vector_type(4)));
typedef _Float16 f16x2 __attribute__((ext_vector_type(2)));
typedef __fp16 fp16x2 __attribute__((ext_vector_type(2)));

__device__ __forceinline__ float frcp(float x)  { return __builtin_amdgcn_rcpf(x); }
__device__ __forceinline__ float fexp2(float x) { return __builtin_amdgcn_exp2f(x); }
__device__ __forceinline__ f32x2 pair(float s)  { f32x2 r = {s, s}; return r; }
__device__ __forceinline__ f32x2 lo2(f32x4 v)   { return __builtin_shufflevector(v, v, 0, 1); }
__device__ __forceinline__ f32x2 hi2(f32x4 v)   { return __builtin_shufflevector(v, v, 2, 3); }
__device__ __forceinline__ f32x4 cat4(f32x2 a, f32x2 b) {
    f32x4 r; r.x = a.x; r.y = a.y; r.z = b.x; r.w = b.y; return r;
}
// f16 packed helpers (compiler emits v_pk_fma_f16 etc. — no inline asm)
__device__ __forceinline__ unsigned b32(f16x2 v) { return __builtin_bit_cast(unsigned, v); }
__device__ __forceinline__ f16x2 hbits(unsigned u) { return __builtin_bit_cast(f16x2, u); }
__device__ __forceinline__ f16x2 hsplat(float s) { _Float16 h = (_Float16)s; f16x2 r = {h, h}; return r; }
__device__ __forceinline__ f16x2 hfma(f16x2 a, f16x2 b, f16x2 c) { return __builtin_elementwise_fma(a, b, c); }
// cvt_pkrtz returns an __fp16 vector type; bit_cast to our _Float16 vector
__device__ __forceinline__ f16x2 pkrtz(float x, float y) {
    fp16x2 t = __builtin_amdgcn_cvt_pkrtz(x, y);
    return __builtin_bit_cast(f16x2, t);
}
__device__ __forceinline__ f32x4 h2f4(f16x2 a, f16x2 b) {
    f32x2 lo = __builtin_convertvector(a, f32x2);
    f32x2 hi = __builtin_convertvector(b, f32x2);
    return cat4(lo, hi);
}

// ---- packed-FP32 VOP3P asm for the f32 gate algebra (round-7 proven;
// round-8 lesson: v_pk_*_f32 sources must be VGPRs, never SGPRs) ----
__device__ __forceinline__ f32x2 pkfma2(f32x2 a, f32x2 b, f32x2 c) {
    f32x2 d;
    asm("v_pk_fma_f32 %0, %1, %2, %3" : "=v"(d) : "v"(a), "v"(b), "v"(c));
    return d;
}
__device__ __forceinline__ f32x2 pkadd2(f32x2 a, f32x2 b) {
    f32x2 d;
    asm("v_pk_add_f32 %0, %1, %2" : "=v"(d) : "v"(a), "v"(b));
    return d;
}
__device__ __forceinline__ f32x2 pksub2(f32x2 a, f32x2 b) {  // a - b
    f32x2 d;
    asm("v_pk_add_f32 %0, %1, %2 neg_lo:[0,1] neg_hi:[0,1]" : "=v"(d) : "v"(a), "v"(b));
    return d;
}
__device__ __forceinline__ f32x2 pkmul2(f32x2 a, f32x2 b) {
    f32x2 d;
    asm("v_pk_mul_f32 %0, %1, %2" : "=v"(d) : "v"(a), "v"(b));
    return d;
}
__device__ __forceinline__ f32x4 pfma_v(f32x4 a, f32x4 b, f32x4 c) {
    return cat4(pkfma2(lo2(a), lo2(b), lo2(c)), pkfma2(hi2(a), hi2(b), hi2(c)));
}
__device__ __forceinline__ f32x4 padd_s(f32x2 s, f32x4 b) {
    return cat4(pkadd2(s, lo2(b)), pkadd2(s, hi2(b)));
}
__device__ __forceinline__ f32x4 psub_s(f32x2 s, f32x4 b) {  // s - b
    return cat4(pksub2(s, lo2(b)), pksub2(s, hi2(b)));
}
__device__ __forceinline__ f32x4 pmul_v(f32x4 a, f32x4 b) {
    return cat4(pkmul2(lo2(a), lo2(b)), pkmul2(hi2(a), hi2(b)));
}

// o = tanh(a)*sigmoid(b); af = -2*log2e*a, ag = -log2e*b pre-scaled (in the
// f16 weights): E1=2^af=e^{-2a}, E2=2^ag=e^{-b}; o=(1-E1)/((1+E1)(1+E2))
__device__ __forceinline__ f32x4 gate4(f32x4 af, f32x4 ag, f32x2 one) {
    f32x4 E1, E2, rc;
    E1.x = fexp2(af.x); E1.y = fexp2(af.y); E1.z = fexp2(af.z); E1.w = fexp2(af.w);
    E2.x = fexp2(ag.x); E2.y = fexp2(ag.y); E2.z = fexp2(ag.z); E2.w = fexp2(ag.w);
    f32x4 d1  = padd_s(one, E1);
    f32x4 den = pfma_v(E2, d1, d1);
    f32x4 num = psub_s(one, E1);
    rc.x = frcp(den.x); rc.y = frcp(den.y); rc.z = frcp(den.z); rc.w = frcp(den.w);
    return pmul_v(num, rc);
}
// conv1->relu->conv2->relu->mu-law expand; exp(|b|*ln256) == exp2(|b|*8)
__device__ __forceinline__ float mulaw(float v, float c1wv, float c1bv, float c2wv, float c2bv) {
    float a  = __builtin_fmaf(c1wv, fmaxf(v, 0.0f), c1bv);
    float b2 = __builtin_fmaf(c2wv, fmaxf(a, 0.0f), c2bv);
    float m  = fexp2(fabsf(b2) * 8.0f) - 1.0f;
    return copysignf(m * (1.0f / 255.0f), b2);
}

// One dilation cycle (10 layers, d=1..512). FULL PACKED-F16 DATAPATH:
// thread owns 3 groups (4 elems each) as f16x2 pairs {hA,hB}; LDS holds the
// same packed words (uint2/group), double-buffered, ONE barrier per layer.
// Conv + residual + skip-accum run as v_pk_fma_f16 on packed words — no
// pack/unpack anywhere in the loop. Only the gate (exp2/rcp) runs in f32
// (4 cvt in, 1 cvt_pkrtz pair out per word-pair), which also removes any
// f16-exp overflow corner. Inter-stage h AND sk handoffs are packed f16.
// Reach-based halo skip: layer k's output only needed at halo G >= 2^(k+1).
// Zero padding: global t<0 <=> (chunk==0 && w==0); f16 zero is exact.
// NOTE: launch_bounds min-waves stays 4 — 8 clamps VGPR to 32 -> spill storm.
template <int STAGE>
__global__ __launch_bounds__(NTHREADS, 4)
void stage_kernel(const void* __restrict__ in_,
                  const float* __restrict__ cw, const float* __restrict__ cb,
                  const float* __restrict__ fw, const float* __restrict__ fb,
                  const float* __restrict__ gw, const float* __restrict__ gb,
                  const float* __restrict__ rw, const float* __restrict__ rb,
                  uint2* __restrict__ hout, uint2* __restrict__ skbuf,
                  float* __restrict__ pout,
                  const float* __restrict__ c1w, const float* __restrict__ c1b,
                  const float* __restrict__ c2w, const float* __restrict__ c2b,
                  float2* __restrict__ blockstats)
{
    __shared__ uint2 bufl[2][NGROUPS];       // 2 x 24 KB packed-f16 tap buffers
    __shared__ float red[NTHREADS / 64];

    const int tid = threadIdx.x;
    const int bid = blockIdx.x;
    const int row = bid / CHUNKS_PER_ROW;
    const int chunk = bid % CHUNKS_PER_ROW;
    const int rowbase = row * T_LEN;
    const int base_t = chunk * CHUNK;
    const bool first = (chunk == 0);
    const f16x2 HZ = hsplat(0.0f);

    // ---- load own groups + publish packed taps to buf 0 ----
    f16x2 hA[3], hB[3];
    if (STAGE == 0) {
        const float* inb = (const float*)in_ + rowbase + base_t - HALO;
        #pragma unroll
        for (int w = 0; w < 3; ++w) {
            int G = tid + w * NTHREADS;
            if (w == 0 && first) { hA[w] = HZ; hB[w] = HZ; }
            else {
                f32x4 v = *(const f32x4*)(inb + 4 * G);
                hA[w] = pkrtz(v.x, v.y);
                hB[w] = pkrtz(v.z, v.w);
            }
            bufl[0][G] = make_uint2(b32(hA[w]), b32(hB[w]));
        }
    } else {
        const uint2* inb = (const uint2*)in_ + ((rowbase + base_t - HALO) >> 2);
        #pragma unroll
        for (int w = 0; w < 3; ++w) {
            int G = tid + w * NTHREADS;
            uint2 u = (w == 0 && first) ? make_uint2(0u, 0u) : inb[G];
            bufl[0][G] = u;
            hA[w] = hbits(u.x); hB[w] = hbits(u.y);
        }
    }
    // skip accumulators for w=1,2 (valid region), packed f16
    f16x2 s1A, s1B, s2A, s2B;
    const int skb = ((rowbase + base_t) >> 2) + tid;
    if (STAGE == 0) { s1A = HZ; s1B = HZ; s2A = HZ; s2B = HZ; }
    else {
        uint2 u1 = skbuf[skb], u2 = skbuf[skb + 1024];
        s1A = hbits(u1.x); s1B = hbits(u1.y);
        s2A = hbits(u2.x); s2B = hbits(u2.y);
    }
    __syncthreads();

    const f32x2 ONE = pair(1.0f);

    if (STAGE == 0) {
        // causal conv (d=1); weight for tap distance m is cw[4-m]
        const f16x2 C0 = hsplat(cw[4]), C1 = hsplat(cw[3]), C2 = hsplat(cw[2]),
                    C3 = hsplat(cw[1]), C4 = hsplat(cw[0]), BB = hsplat(cb[0]);
        #pragma unroll
        for (int w = 0; w < 3; ++w) {
            int G = tid + w * NTHREADS;
            int gm = G - 1; if (w == 0) gm = gm < 0 ? 0 : gm;  // junk-in-halo OK
            uint2 P = bufl[0][gm];
            unsigned uA = b32(hA[w]), uB = b32(hB[w]);
            unsigned t1A = __builtin_amdgcn_perm(uA, P.y, 0x05040302u);
            unsigned t1B = __builtin_amdgcn_perm(uB, uA, 0x05040302u);
            unsigned t3A = __builtin_amdgcn_perm(P.y, P.x, 0x05040302u);
            f16x2 aA = hfma(C0, hA[w], BB);
            f16x2 aB = hfma(C0, hB[w], BB);
            aA = hfma(C1, hbits(t1A), aA); aB = hfma(C1, hbits(t1B), aB);
            aA = hfma(C2, hbits(P.y), aA); aB = hfma(C2, hbits(uA), aB);
            aA = hfma(C3, hbits(t3A), aA); aB = hfma(C3, hbits(t1A), aB);
            aA = hfma(C4, hbits(P.x), aA); aB = hfma(C4, hbits(P.y), aB);
            if (w == 0 && first) { aA = HZ; aB = HZ; }
            hA[w] = aA; hB[w] = aB;
            bufl[1][G] = make_uint2(b32(aA), b32(aB));
        }
        __syncthreads();
    }

    // ---- 10 dilated gated layers, one barrier each; c compile-time ----
    #pragma unroll
    for (int k = 0; k < 10; ++k) {
        const int c = (STAGE == 0) ? ((k + 1) & 1) : (k & 1);
        const int d = 1 << k;
        const int L = STAGE * 10 + k;
        const float* fwL = fw + 5 * L;
        const float* gwL = gw + 5 * L;
        // f16 weights pre-scaled so the gate's exp2 needs no extra multiply
        const f16x2 WF0 = hsplat(fwL[4] * NEG2LOG2E), WF1 = hsplat(fwL[3] * NEG2LOG2E),
                    WF2 = hsplat(fwL[2] * NEG2LOG2E), WF3 = hsplat(fwL[1] * NEG2LOG2E),
                    WF4 = hsplat(fwL[0] * NEG2LOG2E);
        const f16x2 WG0 = hsplat(gwL[4] * NEGLOG2E), WG1 = hsplat(gwL[3] * NEGLOG2E),
                    WG2 = hsplat(gwL[2] * NEGLOG2E), WG3 = hsplat(gwL[1] * NEGLOG2E),
                    WG4 = hsplat(gwL[0] * NEGLOG2E);
        const f16x2 FB = hsplat(fb[L] * NEG2LOG2E), GB = hsplat(gb[L] * NEGLOG2E);
        const f16x2 RW = hsplat(rw[L]), RB = hsplat(rb[L]);
        const uint2* __restrict__ bufc = bufl[c];
        uint2* __restrict__ bufd = bufl[c ^ 1];

        #pragma unroll
        for (int w = 0; w < 3; ++w) {
            const int G = tid + w * NTHREADS;
            if (w == 0 && tid < (2 << k)) continue;  // reach expired (k=9: all of w=0)
            f16x2 cA = hA[w], cB = hB[w];
            f16x2 t1a, t1b, t2a, t2b, t3a, t3b, t4a, t4b;
            if (d >= 4) {
                const int DG = d >> 2;               // taps stay group-aligned
                const uint2* bp = bufc + (G - 4 * DG);
                uint2 U4 = bp[0], U3 = bp[DG], U2 = bp[2 * DG], U1 = bp[3 * DG];
                t1a = hbits(U1.x); t1b = hbits(U1.y);
                t2a = hbits(U2.x); t2b = hbits(U2.y);
                t3a = hbits(U3.x); t3b = hbits(U3.y);
                t4a = hbits(U4.x); t4b = hbits(U4.y);
            } else if (d == 1) {
                uint2 P = bufc[G - 1];
                unsigned uA = b32(cA);
                unsigned w1A = __builtin_amdgcn_perm(uA, P.y, 0x05040302u);
                unsigned w1B = __builtin_amdgcn_perm(b32(cB), uA, 0x05040302u);
                unsigned w3A = __builtin_amdgcn_perm(P.y, P.x, 0x05040302u);
                t1a = hbits(w1A); t1b = hbits(w1B);
                t2a = hbits(P.y); t2b = cA;
                t3a = hbits(w3A); t3b = hbits(w1A);
                t4a = hbits(P.x); t4b = hbits(P.y);
            } else { // d == 2 — all word-aligned
                uint2 P = bufc[G - 1], Q = bufc[G - 2];
                t1a = hbits(P.y); t1b = cA;
                t2a = hbits(P.x); t2b = hbits(P.y);
                t3a = hbits(Q.y); t3b = hbits(P.x);
                t4a = hbits(Q.x); t4b = hbits(Q.y);
            }
            // packed-f16 conv (accumulates the pre-scaled logits)
            f16x2 afA = hfma(WF0, cA, FB), afB = hfma(WF0, cB, FB);
            afA = hfma(WF1, t1a, afA); afB = hfma(WF1, t1b, afB);
            afA = hfma(WF2, t2a, afA); afB = hfma(WF2, t2b, afB);
            afA = hfma(WF3, t3a, afA); afB = hfma(WF3, t3b, afB);
            afA = hfma(WF4, t4a, afA); afB = hfma(WF4, t4b, afB);
            f16x2 agA = hfma(WG0, cA, GB), agB = hfma(WG0, cB, GB);
            agA = hfma(WG1, t1a, agA); agB = hfma(WG1, t1b, agB);
            agA = hfma(WG2, t2a, agA); agB = hfma(WG2, t2b, agB);
            agA = hfma(WG3, t3a, agA); agB = hfma(WG3, t3b, agB);
            agA = hfma(WG4, t4a, agA); agB = hfma(WG4, t4b, agB);
            // gate in f32 (exp2/rcp range-safe), back to packed f16
            f32x4 o = gate4(h2f4(afA, afB), h2f4(agA, agB), ONE);
            f16x2 oA = pkrtz(o.x, o.y), oB = pkrtz(o.z, o.w);
            f16x2 nA = hfma(RW, oA, cA + RB);
            f16x2 nB = hfma(RW, oB, cB + RB);
            if (w == 0 && first) { nA = HZ; nB = HZ; }   // keep t<0 pad exact 0
            hA[w] = nA; hB[w] = nB;
            if (k < 9) bufd[G] = make_uint2(b32(nA), b32(nB));
            if (w == 1) { s1A = s1A + oA; s1B = s1B + oB; }
            if (w == 2) { s2A = s2A + oA; s2B = s2B + oB; }
        }
        if (k < 9) __syncthreads();
    }

    if (STAGE < 2) {
        uint2* hp = hout + ((rowbase + base_t) >> 2);
        hp[tid]        = make_uint2(b32(hA[1]), b32(hB[1]));   // packed f16 handoff
        hp[tid + 1024] = make_uint2(b32(hA[2]), b32(hB[2]));
        skbuf[skb]        = make_uint2(b32(s1A), b32(s1B));
        skbuf[skb + 1024] = make_uint2(b32(s2A), b32(s2B));
    } else {
        // fused epilogue + per-block (max, sum-exp) stats
        const float c1wv = c1w[0], c1bv = c1b[0], c2wv = c2w[0], c2bv = c2b[0];
        f32x4 sk1 = h2f4(s1A, s1B), sk2 = h2f4(s2A, s2B);
        f32x4 p1, p2;
        p1.x = mulaw(sk1.x, c1wv, c1bv, c2wv, c2bv);
        p1.y = mulaw(sk1.y, c1wv, c1bv, c2wv, c2bv);
        p1.z = mulaw(sk1.z, c1wv, c1bv, c2wv, c2bv);
        p1.w = mulaw(sk1.w, c1wv, c1bv, c2wv, c2bv);
        p2.x = mulaw(sk2.x, c1wv, c1bv, c2wv, c2bv);
        p2.y = mulaw(sk2.y, c1wv, c1bv, c2wv, c2bv);
        p2.z = mulaw(sk2.z, c1wv, c1bv, c2wv, c2bv);
        p2.w = mulaw(sk2.w, c1wv, c1bv, c2wv, c2bv);
        *(f32x4*)(pout + rowbase + base_t + 4 * tid)        = p1;
        *(f32x4*)(pout + rowbase + base_t + 4096 + 4 * tid) = p2;

        float pmax = fmaxf(fmaxf(fmaxf(p1.x, p1.y), fmaxf(p1.z, p1.w)),
                           fmaxf(fmaxf(p2.x, p2.y), fmaxf(p2.z, p2.w)));
        #pragma unroll
        for (int off = 32; off; off >>= 1) pmax = fmaxf(pmax, __shfl_xor(pmax, off, 64));
        if ((tid & 63) == 0) red[tid >> 6] = pmax;
        __syncthreads();
        float bmax = red[0];
        #pragma unroll
        for (int i = 1; i < NTHREADS / 64; ++i) bmax = fmaxf(bmax, red[i]);
        __syncthreads();   // red reused below

        float ps = fexp2((p1.x - bmax) * LOG2E) + fexp2((p1.y - bmax) * LOG2E)
                 + fexp2((p1.z - bmax) * LOG2E) + fexp2((p1.w - bmax) * LOG2E)
                 + fexp2((p2.x - bmax) * LOG2E) + fexp2((p2.y - bmax) * LOG2E)
                 + fexp2((p2.z - bmax) * LOG2E) + fexp2((p2.w - bmax) * LOG2E);
        #pragma unroll
        for (int off = 32; off; off >>= 1) ps += __shfl_xor(ps, off, 64);
        if ((tid & 63) == 0) red[tid >> 6] = ps;
        __syncthreads();
        if (tid == 0) {
            float s = 0.0f;
            #pragma unroll
            for (int i = 0; i < NTHREADS / 64; ++i) s += red[i];
            blockstats[bid] = make_float2(bmax, s);
        }
    }
}

// 8 blocks (one per row) x 64 threads: reduce 32 block-stats -> (rowmax, 1/rowsum)
__global__ __launch_bounds__(64)
void combine_kernel(const float2* __restrict__ bs, float2* __restrict__ rs)
{
    const int row = blockIdx.x;
    const int lane = threadIdx.x;
    float bm = -3.0e38f, s = 0.0f;
    if (lane < CHUNKS_PER_ROW) {
        float2 v = bs[row * CHUNKS_PER_ROW + lane];
        bm = v.x; s = v.y;
    }
    float m = bm;
    #pragma unroll
    for (int off = 32; off; off >>= 1) m = fmaxf(m, __shfl_xor(m, off, 64));
    float cc = s * fexp2((bm - m) * LOG2E);
    #pragma unroll
    for (int off = 32; off; off >>= 1) cc += __shfl_xor(cc, off, 64);
    if (lane == 0) rs[row] = make_float2(m, 1.0f / cc);
}

__global__ __launch_bounds__(NTHREADS)
void norm_kernel(float* __restrict__ p, const float2* __restrict__ rs)
{
    const int tid = threadIdx.x, bid = blockIdx.x;
    const int row = bid / CHUNKS_PER_ROW;
    const float2 st = rs[row];
    const int base = row * T_LEN + (bid % CHUNKS_PER_ROW) * CHUNK + 4 * tid;
    #pragma unroll
    for (int part = 0; part < 2; ++part) {
        float* q = p + base + part * 4096;
        f32x4 v = *(const f32x4*)q;
        v.x = fexp2((v.x - st.x) * LOG2E) * st.y;
        v.y = fexp2((v.y - st.x) * LOG2E) * st.y;
        v.z = fexp2((v.z - st.x) * LOG2E) * st.y;
        v.w = fexp2((v.w - st.x) * LOG2E) * st.y;
        *(f32x4*)q = v;
    }
}

extern "C" void kernel_launch(void* const* d_in, const int* in_sizes, int n_in,
                              void* d_out, int out_size, void* d_ws, size_t ws_size,
                              hipStream_t stream)
{
    (void)in_sizes; (void)n_in; (void)out_size; (void)ws_size;
    const float* x   = (const float*)d_in[0];
    const float* cw  = (const float*)d_in[1];
    const float* cb  = (const float*)d_in[2];
    const float* fw  = (const float*)d_in[3];
    const float* fb  = (const float*)d_in[4];
    const float* gw  = (const float*)d_in[5];
    const float* gb  = (const float*)d_in[6];
    const float* rw  = (const float*)d_in[7];
    const float* rb  = (const float*)d_in[8];
    const float* c1w = (const float*)d_in[9];
    const float* c1b = (const float*)d_in[10];
    const float* c2w = (const float*)d_in[11];
    const float* c2b = (const float*)d_in[12];
    float* out = (float*)d_out;

    const size_t NTOT = (size_t)B_SZ * T_LEN;
    uint2*  hA = (uint2*)d_ws;                                  // 4.2 MB packed f16
    uint2*  hB = (uint2*)((char*)d_ws + 2 * NTOT);              // 4.2 MB
    uint2*  sk = (uint2*)((char*)d_ws + 4 * NTOT);              // 4.2 MB packed f16
    float2* bs = (float2*)((char*)d_ws + 6 * NTOT);             // 2 KB
    float2* rs = (float2*)((char*)d_ws + 6 * NTOT + 8192);      // 64 B

    stage_kernel<0><<<NBLOCKS, NTHREADS, 0, stream>>>(x,  cw, cb, fw, fb, gw, gb, rw, rb,
                                                      hA, sk, out, c1w, c1b, c2w, c2b, bs);
    stage_kernel<1><<<NBLOCKS, NTHREADS, 0, stream>>>(hA, cw, cb, fw, fb, gw, gb, rw, rb,
                                                      hB, sk, out, c1w, c1b, c2w, c2b, bs);
    stage_kernel<2><<<NBLOCKS, NTHREADS, 0, stream>>>(hB, cw, cb, fw, fb, gw, gb, rw, rb,
                                                      nullptr, sk, out, c1w, c1b, c2w, c2b, bs);
    combine_kernel<<<B_SZ, 64, 0, stream>>>(bs, rs);
    norm_kernel<<<NBLOCKS, NTHREADS, 0, stream>>>(out, rs);
}